// Round 4
// baseline (256.683 us; speedup 1.0000x reference)
//
#include <hip/hip_runtime.h>
#include <hip/hip_bf16.h>

#define BB 32
#define LL 100
#define DD 200      // MEM
#define KIN 360
#define NP 3200
#define RNUM 40
#define LT 13
#define NBLK 256
#define NTHR 512

// ws float offsets
#define OFF_XA    0
#define OFF_XB    640000
#define OFF_WPT   1280000
#define OFF_W0T   1352000
#define OFF_W1T   1392000
#define OFF_INVD  1432000
#define OFF_DEPP  1435200   // 4000 u32 (2000 uint2, bf16-packed deprel)
#define OFF_ADJP  1439200   // 80000 u32 (byte-packed adj)
#define OFF_BAR   1519200   // 2 u32 (grid barrier)

__device__ __forceinline__ void fma4(float4& a, const float4& w, float s) {
    a.x = fmaf(w.x, s, a.x);
    a.y = fmaf(w.y, s, a.y);
    a.z = fmaf(w.z, s, a.z);
    a.w = fmaf(w.w, s, a.w);
}
__device__ __forceinline__ unsigned bf16rn(float f) {
    unsigned u = __float_as_uint(f);
    return (u + 0x7fffu + ((u >> 16) & 1u)) >> 16;
}
__device__ __forceinline__ unsigned pk2(float a, float b) {
    return bf16rn(a) | (bf16rn(b) << 16);
}
__device__ __forceinline__ float lo16(unsigned u) { return __uint_as_float(u << 16); }
__device__ __forceinline__ float hi16(unsigned u) { return __uint_as_float(u & 0xffff0000u); }

// device-scope grid barrier: bar[0]=count, bar[1]=generation (memset to 0 each launch)
__device__ __forceinline__ void grid_barrier(unsigned* bar) {
    __syncthreads();
    if (threadIdx.x == 0) {
        __threadfence();
        unsigned g = __hip_atomic_load(bar + 1, __ATOMIC_ACQUIRE, __HIP_MEMORY_SCOPE_AGENT);
        unsigned a = __hip_atomic_fetch_add(bar, 1u, __ATOMIC_ACQ_REL, __HIP_MEMORY_SCOPE_AGENT);
        if (a == NBLK - 1) {
            __hip_atomic_store(bar, 0u, __ATOMIC_RELEASE, __HIP_MEMORY_SCOPE_AGENT);
            __hip_atomic_fetch_add(bar + 1, 1u, __ATOMIC_RELEASE, __HIP_MEMORY_SCOPE_AGENT);
        } else {
            while (__hip_atomic_load(bar + 1, __ATOMIC_ACQUIRE, __HIP_MEMORY_SCOPE_AGENT) == g)
                __builtin_amdgcn_s_sleep(1);
        }
        __threadfence();
    }
    __syncthreads();
}

__global__ __launch_bounds__(NTHR, 4) void fused_kernel(
        const int* __restrict__ adj, const int* __restrict__ words,
        const int* __restrict__ pos, const int* __restrict__ ner,
        const float* __restrict__ emb, const float* __restrict__ pose,
        const float* __restrict__ nere, const float* __restrict__ dep,
        const float* __restrict__ Wp, const float* __restrict__ bp,
        const float* __restrict__ W0, const float* __restrict__ b0,
        const float* __restrict__ W1, const float* __restrict__ b1,
        float* ws, float* out) {
    __shared__ alignas(16) char smem[48768];
    unsigned* bar = (unsigned*)(ws + OFF_BAR);
    float* xA = ws + OFF_XA;
    float* xB = ws + OFF_XB;
    float* wpT = ws + OFF_WPT;
    float* w0T = ws + OFF_W0T;
    float* w1T = ws + OFF_W1T;
    float* invd_g = ws + OFF_INVD;
    uint2* depp_g = (uint2*)(ws + OFF_DEPP);
    unsigned* adjp_g = (unsigned*)(ws + OFF_ADJP);

    int bid = blockIdx.x, tid = threadIdx.x;

    // ================= Phase A: transposes + prep + packing (flat 126400 items) ==========
    {
        int t = bid * NTHR + tid;
        if (t < 18000) {                       // WpT [360][200]
            int k = t / 50, o = (t % 50) * 4;
            float4 v;
            v.x = Wp[(size_t)(o + 0) * KIN + k];
            v.y = Wp[(size_t)(o + 1) * KIN + k];
            v.z = Wp[(size_t)(o + 2) * KIN + k];
            v.w = Wp[(size_t)(o + 3) * KIN + k];
            ((float4*)wpT)[t] = v;
        } else if (t < 28000) {                // W0T [200][200]
            int q = t - 18000;
            int k = q / 50, o = (q % 50) * 4;
            float4 v;
            v.x = W0[(size_t)(o + 0) * DD + k];
            v.y = W0[(size_t)(o + 1) * DD + k];
            v.z = W0[(size_t)(o + 2) * DD + k];
            v.w = W0[(size_t)(o + 3) * DD + k];
            ((float4*)w0T)[q] = v;
        } else if (t < 38000) {                // W1T
            int q = t - 28000;
            int k = q / 50, o = (q % 50) * 4;
            float4 v;
            v.x = W1[(size_t)(o + 0) * DD + k];
            v.y = W1[(size_t)(o + 1) * DD + k];
            v.z = W1[(size_t)(o + 2) * DD + k];
            v.w = W1[(size_t)(o + 3) * DD + k];
            ((float4*)w1T)[q] = v;
        } else if (t < 44400) {                // prep: invd + mask, split-2 per (b,l)
            int item = t - 38000;
            int half = item & 1, pl = item >> 1;
            int b = pl / LL, l = pl % LL;
            const int4* row = (const int4*)(adj + (size_t)pl * LL);
            int q0 = half ? 13 : 0, q1 = half ? 25 : 13;
            int rc = 0;
            for (int i = q0; i < q1; ++i) {
                int4 a = row[i];
                rc += (a.x != 0) + (a.y != 0) + (a.z != 0) + (a.w != 0);
            }
            const int* base = adj + (size_t)b * LL * LL + l;
            int cc = 0;
            for (int m = half * 50; m < half * 50 + 50; ++m) cc += (base[(size_t)m * LL] != 0);
            rc += __shfl_xor(rc, 1);
            cc += __shfl_xor(cc, 1);
            if (!half) {
                invd_g[pl] = 1.0f / (float)(rc + 1);
                out[(size_t)NP * DD + pl] = (rc + cc == 0) ? 1.0f : 0.0f;
            }
        } else if (t < 46400) {                // deprel bf16 pack (2000 quads)
            int i = t - 44400;
            float4 v = ((const float4*)dep)[i];
            depp_g[i] = make_uint2(pk2(v.x, v.y), pk2(v.z, v.w));
        } else if (t < 126400) {               // adj byte-pack: all 3200 rows x 25 quads
            int i = t - 46400;
            int4 a = ((const int4*)adj)[i];
            adjp_g[i] = (unsigned)a.x | ((unsigned)a.y << 8) |
                        ((unsigned)a.z << 16) | ((unsigned)a.w << 24);
        }
    }

    grid_barrier(bar);

    // ================= Phase B: embed gather + proj GEMV (blocks 0..199) =================
    // Block = 16 positions; 2 clusters of 4 waves; wave = 8 pos x K-chunk (quads
    // 0-23 / 24-47 / 48-71 / 72-89); two-step LDS reduce.
    if (bid < 200) {
        float* es = (float*)smem;                    // 16*360 f32 = 23040 B
        float4* red = (float4*)(smem + 23040);       // 2 clusters * 2 slots * 400 = 25600 B
        int pbase = bid * 16;
        float2* es2 = (float2*)es;
        for (int idx = tid; idx < 16 * 180; idx += NTHR) {
            int p = idx / 180, j2 = idx % 180;
            int gp = pbase + p;
            float2 v;
            if (j2 < 150)      v = ((const float2*)emb)[(size_t)words[gp] * 150 + j2];
            else if (j2 < 165) v = ((const float2*)pose)[pos[gp] * 15 + (j2 - 150)];
            else               v = ((const float2*)nere)[ner[gp] * 15 + (j2 - 165)];
            es2[idx] = v;
        }
        __syncthreads();

        int lane = tid & 63, wv = tid >> 6;
        int c = wv >> 2, w4 = wv & 3;
        bool act = lane < 50;
        int oq = act ? lane : 49;
        int kq0 = w4 * 24;
        int kqn = (w4 < 3) ? 24 : 18;
        const float4* wt4 = (const float4*)wpT;
        const float4* es4 = (const float4*)es;
        float4 a[8];
        #pragma unroll
        for (int p = 0; p < 8; ++p) a[p] = make_float4(0.f, 0.f, 0.f, 0.f);
        for (int k = 0; k < kqn; ++k) {
            int kq = kq0 + k;
            float4 w0 = wt4[(size_t)(4 * kq + 0) * 50 + oq];
            float4 w1 = wt4[(size_t)(4 * kq + 1) * 50 + oq];
            float4 w2 = wt4[(size_t)(4 * kq + 2) * 50 + oq];
            float4 w3 = wt4[(size_t)(4 * kq + 3) * 50 + oq];
            #pragma unroll
            for (int p = 0; p < 8; ++p) {
                float4 s = es4[(c * 8 + p) * 90 + kq];   // wave-uniform broadcast
                fma4(a[p], w0, s.x); fma4(a[p], w1, s.y);
                fma4(a[p], w2, s.z); fma4(a[p], w3, s.w);
            }
        }
        float4* redc = red + c * 800;
        if (w4 >= 2 && act) {
            #pragma unroll
            for (int p = 0; p < 8; ++p) redc[(w4 - 2) * 400 + p * 50 + oq] = a[p];
        }
        __syncthreads();
        if (w4 < 2 && act) {
            #pragma unroll
            for (int p = 0; p < 8; ++p) {
                float4 r = redc[w4 * 400 + p * 50 + oq];
                r.x += a[p].x; r.y += a[p].y; r.z += a[p].z; r.w += a[p].w;
                redc[w4 * 400 + p * 50 + oq] = r;
            }
        }
        __syncthreads();
        for (int t2 = tid; t2 < 800; t2 += NTHR) {
            int pp = t2 / 50, oq2 = t2 % 50;
            float4* rc2 = red + (pp >> 3) * 800;
            float4 v0 = rc2[(pp & 7) * 50 + oq2];
            float4 v1 = rc2[400 + (pp & 7) * 50 + oq2];
            float4 bb = ((const float4*)bp)[oq2];
            float4 v;
            v.x = v0.x + v1.x + bb.x; v.y = v0.y + v1.y + bb.y;
            v.z = v0.z + v1.z + bb.z; v.w = v0.w + v1.w + bb.w;
            ((float4*)xA)[(size_t)(pbase + pp) * 50 + oq2] = v;
        }
    }

    // ================= Phases C/D: the two GCN layers =================
    uint2* deps_b = (uint2*)smem;                 // 16000 B
    unsigned* adjp = (unsigned*)(smem + 16000);   //  1300 B
    float4* Sh = (float4*)(smem + 17312);         // 20800 B
    float4* Sfin = (float4*)(smem + 38112);       // 10400 B
    int b = bid >> 3, tile = bid & 7;
    int l0 = tile * LT;
    int lcnt = min(LT, LL - l0);
    int lane = tid & 63, wv = tid >> 6;
    int lg = wv & 3, mh = wv >> 2;
    bool act = lane < 50;
    int dq = lane;

    for (int layer = 0; layer < 2; ++layer) {
        grid_barrier(bar);
        const float* xin = layer ? xB : xA;
        float* xout = layer ? out : xB;
        const float* wt = layer ? w1T : w0T;
        const float* bias = layer ? b1 : b0;
        const float4* x4 = (const float4*)xin;

        if (layer == 0) {   // stage layer-invariant LDS once (persists across barrier)
            for (int i = tid; i < 2000; i += NTHR) deps_b[i] = depp_g[i];
            for (int i = tid; i < lcnt * 25; i += NTHR)
                adjp[i] = adjp_g[(b * LL + l0) * 25 + i];
        }
        __syncthreads();

        // ---- Ax over m-half ----
        float4 acc[4];
        #pragma unroll
        for (int i = 0; i < 4; ++i) acc[i] = make_float4(0.f, 0.f, 0.f, 0.f);
        if (act) {
            int mg0 = mh ? 13 : 0, mg1 = mh ? 25 : 13;
            for (int mg = mg0; mg < mg1; ++mg) {
                unsigned ap[4];
                #pragma unroll
                for (int i = 0; i < 4; ++i) {
                    int li = lg + 4 * i;
                    ap[i] = (li < lcnt) ? adjp[li * 25 + mg] : 0u;
                }
                #pragma unroll
                for (int mm = 0; mm < 4; ++mm) {
                    float4 xv = x4[(size_t)(b * LL + 4 * mg + mm) * 50 + dq];
                    #pragma unroll
                    for (int i = 0; i < 4; ++i) {
                        unsigned r = (ap[i] >> (8 * mm)) & 0xffu;
                        uint2 dv = deps_b[r * 50 + dq];
                        acc[i].x = fmaf(lo16(dv.x), xv.x, acc[i].x);
                        acc[i].y = fmaf(hi16(dv.x), xv.y, acc[i].y);
                        acc[i].z = fmaf(lo16(dv.y), xv.z, acc[i].z);
                        acc[i].w = fmaf(hi16(dv.y), xv.w, acc[i].w);
                    }
                }
            }
            #pragma unroll
            for (int i = 0; i < 4; ++i) {
                int li = lg + 4 * i;
                if (li < lcnt) Sh[mh * 650 + li * 50 + dq] = acc[i];
            }
        }
        __syncthreads();

        // ---- reduce halves + fp32 residual ----
        for (int t2 = tid; t2 < 650; t2 += NTHR) {
            int li = t2 / 50;
            if (li < lcnt) {
                float4 s0 = Sh[t2], s1 = Sh[650 + t2];
                float4 xr = x4[(size_t)(b * LL + l0 + li) * 50 + (t2 % 50)];
                float4 s;
                s.x = s0.x + s1.x + xr.x; s.y = s0.y + s1.y + xr.y;
                s.z = s0.z + s1.z + xr.z; s.w = s0.w + s1.w + xr.w;
                Sfin[t2] = s;
            }
        }
        __syncthreads();

        // ---- GEMV over k-half ----
        const float4* wt4 = (const float4*)wt;
        int oq = act ? lane : 49;
        float4 ba[4];
        #pragma unroll
        for (int i = 0; i < 4; ++i) ba[i] = make_float4(0.f, 0.f, 0.f, 0.f);
        for (int k = 0; k < 25; ++k) {
            int kq = mh * 25 + k;
            float4 w0 = wt4[(size_t)(4 * kq + 0) * 50 + oq];
            float4 w1 = wt4[(size_t)(4 * kq + 1) * 50 + oq];
            float4 w2 = wt4[(size_t)(4 * kq + 2) * 50 + oq];
            float4 w3 = wt4[(size_t)(4 * kq + 3) * 50 + oq];
            #pragma unroll
            for (int i = 0; i < 4; ++i) {
                int li = lg + 4 * i;
                int lic = li < lcnt ? li : lcnt - 1;
                float4 s = Sfin[lic * 50 + kq];   // wave-uniform broadcast
                fma4(ba[i], w0, s.x); fma4(ba[i], w1, s.y);
                fma4(ba[i], w2, s.z); fma4(ba[i], w3, s.w);
            }
        }
        if (act) {
            #pragma unroll
            for (int i = 0; i < 4; ++i) {
                int li = lg + 4 * i;
                if (li < lcnt) Sh[mh * 650 + li * 50 + oq] = ba[i];
            }
        }
        __syncthreads();

        for (int t2 = tid; t2 < 650; t2 += NTHR) {
            int li = t2 / 50, oq2 = t2 % 50;
            if (li < lcnt) {
                float4 v0 = Sh[t2], v1 = Sh[650 + t2];
                float4 bb = ((const float4*)bias)[oq2];
                int p = b * LL + l0 + li;
                float sc = invd_g[p];
                float4 v;
                v.x = fmaxf((v0.x + v1.x + 2.f * bb.x) * sc, 0.f);
                v.y = fmaxf((v0.y + v1.y + 2.f * bb.y) * sc, 0.f);
                v.z = fmaxf((v0.z + v1.z + 2.f * bb.z) * sc, 0.f);
                v.w = fmaxf((v0.w + v1.w + 2.f * bb.w) * sc, 0.f);
                ((float4*)xout)[(size_t)p * 50 + oq2] = v;
            }
        }
        __syncthreads();   // protect Sh before next layer reuses smem
    }
}

extern "C" void kernel_launch(void* const* d_in, const int* in_sizes, int n_in,
                              void* d_out, int out_size, void* d_ws, size_t ws_size,
                              hipStream_t stream) {
    const int*   adj   = (const int*)d_in[0];
    const int*   words = (const int*)d_in[1];
    const int*   pos   = (const int*)d_in[2];
    const int*   ner   = (const int*)d_in[3];
    const float* emb   = (const float*)d_in[4];
    const float* pose  = (const float*)d_in[5];
    const float* nere  = (const float*)d_in[6];
    const float* dep   = (const float*)d_in[7];
    const float* Wp    = (const float*)d_in[8];
    const float* bp    = (const float*)d_in[9];
    const float* W0    = (const float*)d_in[10];
    const float* b0    = (const float*)d_in[11];
    const float* W1    = (const float*)d_in[12];
    const float* b1    = (const float*)d_in[13];
    float* out = (float*)d_out;
    float* ws  = (float*)d_ws;

    hipMemsetAsync(ws + OFF_BAR, 0, 8, stream);   // reset grid barrier
    fused_kernel<<<NBLK, NTHR, 0, stream>>>(adj, words, pos, ner, emb, pose, nere,
                                            dep, Wp, bp, W0, b0, W1, b1, ws, out);
}

// Round 5
// 137.709 us; speedup vs baseline: 1.8640x; 1.8640x over previous
//
#include <hip/hip_runtime.h>
#include <hip/hip_bf16.h>

#define BB 32
#define LL 100
#define DD 200      // MEM
#define KIN 360
#define NP 3200
#define RNUM 40
#define LT 13
#define NBLK 256
#define NTHR 512

// ws float offsets
#define OFF_XA    0
#define OFF_XB    640000
#define OFF_WPT   1280000
#define OFF_W0T   1352000
#define OFF_W1T   1392000
#define OFF_INVD  1432000
#define OFF_DEPP  1435200   // 4000 u32 (2000 uint2, bf16-packed deprel)
#define OFF_ADJP  1439200   // 80000 u32 (byte-packed adj)
#define OFF_BAR   1519200   // 2 u32 (grid barrier)

__device__ __forceinline__ void fma4(float4& a, const float4& w, float s) {
    a.x = fmaf(w.x, s, a.x);
    a.y = fmaf(w.y, s, a.y);
    a.z = fmaf(w.z, s, a.z);
    a.w = fmaf(w.w, s, a.w);
}
__device__ __forceinline__ unsigned bf16rn(float f) {
    unsigned u = __float_as_uint(f);
    return (u + 0x7fffu + ((u >> 16) & 1u)) >> 16;
}
__device__ __forceinline__ unsigned pk2(float a, float b) {
    return bf16rn(a) | (bf16rn(b) << 16);
}
__device__ __forceinline__ float lo16(unsigned u) { return __uint_as_float(u << 16); }
__device__ __forceinline__ float hi16(unsigned u) { return __uint_as_float(u & 0xffff0000u); }

// device-scope grid barrier: bar[0]=count, bar[1]=generation (memset to 0 each launch).
// Spin is RELAXED (no per-poll cache invalidate); release via the ACQ_REL fetch_add on
// arrival; exactly ONE acquire fence per block after resolution.
__device__ __forceinline__ void grid_barrier(unsigned* bar) {
    __syncthreads();
    if (threadIdx.x == 0) {
        unsigned g = __hip_atomic_load(bar + 1, __ATOMIC_RELAXED, __HIP_MEMORY_SCOPE_AGENT);
        unsigned a = __hip_atomic_fetch_add(bar, 1u, __ATOMIC_ACQ_REL, __HIP_MEMORY_SCOPE_AGENT);
        if (a == NBLK - 1) {
            __hip_atomic_store(bar, 0u, __ATOMIC_RELAXED, __HIP_MEMORY_SCOPE_AGENT);
            __hip_atomic_fetch_add(bar + 1, 1u, __ATOMIC_RELEASE, __HIP_MEMORY_SCOPE_AGENT);
        } else {
            while (__hip_atomic_load(bar + 1, __ATOMIC_RELAXED, __HIP_MEMORY_SCOPE_AGENT) == g)
                __builtin_amdgcn_s_sleep(8);
        }
        __builtin_amdgcn_fence(__ATOMIC_ACQUIRE, "agent");
    }
    __syncthreads();
}

__global__ __launch_bounds__(NTHR, 4) void fused_kernel(
        const int* __restrict__ adj, const int* __restrict__ words,
        const int* __restrict__ pos, const int* __restrict__ ner,
        const float* __restrict__ emb, const float* __restrict__ pose,
        const float* __restrict__ nere, const float* __restrict__ dep,
        const float* __restrict__ Wp, const float* __restrict__ bp,
        const float* __restrict__ W0, const float* __restrict__ b0,
        const float* __restrict__ W1, const float* __restrict__ b1,
        float* ws, float* out) {
    __shared__ alignas(16) char smem[48768];
    unsigned* bar = (unsigned*)(ws + OFF_BAR);
    float* xA = ws + OFF_XA;
    float* xB = ws + OFF_XB;
    float* wpT = ws + OFF_WPT;
    float* w0T = ws + OFF_W0T;
    float* w1T = ws + OFF_W1T;
    float* invd_g = ws + OFF_INVD;
    uint2* depp_g = (uint2*)(ws + OFF_DEPP);
    unsigned* adjp_g = (unsigned*)(ws + OFF_ADJP);

    int bid = blockIdx.x, tid = threadIdx.x;

    // ================= Phase A: transposes + prep + packing (flat 126400 items) ==========
    {
        int t = bid * NTHR + tid;
        if (t < 18000) {                       // WpT [360][200]
            int k = t / 50, o = (t % 50) * 4;
            float4 v;
            v.x = Wp[(size_t)(o + 0) * KIN + k];
            v.y = Wp[(size_t)(o + 1) * KIN + k];
            v.z = Wp[(size_t)(o + 2) * KIN + k];
            v.w = Wp[(size_t)(o + 3) * KIN + k];
            ((float4*)wpT)[t] = v;
        } else if (t < 28000) {                // W0T [200][200]
            int q = t - 18000;
            int k = q / 50, o = (q % 50) * 4;
            float4 v;
            v.x = W0[(size_t)(o + 0) * DD + k];
            v.y = W0[(size_t)(o + 1) * DD + k];
            v.z = W0[(size_t)(o + 2) * DD + k];
            v.w = W0[(size_t)(o + 3) * DD + k];
            ((float4*)w0T)[q] = v;
        } else if (t < 38000) {                // W1T
            int q = t - 28000;
            int k = q / 50, o = (q % 50) * 4;
            float4 v;
            v.x = W1[(size_t)(o + 0) * DD + k];
            v.y = W1[(size_t)(o + 1) * DD + k];
            v.z = W1[(size_t)(o + 2) * DD + k];
            v.w = W1[(size_t)(o + 3) * DD + k];
            ((float4*)w1T)[q] = v;
        } else if (t < 44400) {                // prep: invd + mask, split-2 per (b,l)
            int item = t - 38000;
            int half = item & 1, pl = item >> 1;
            int b = pl / LL, l = pl % LL;
            const int4* row = (const int4*)(adj + (size_t)pl * LL);
            int q0 = half ? 13 : 0, q1 = half ? 25 : 13;
            int rc = 0;
            for (int i = q0; i < q1; ++i) {
                int4 a = row[i];
                rc += (a.x != 0) + (a.y != 0) + (a.z != 0) + (a.w != 0);
            }
            const int* base = adj + (size_t)b * LL * LL + l;
            int cc = 0;
            for (int m = half * 50; m < half * 50 + 50; ++m) cc += (base[(size_t)m * LL] != 0);
            rc += __shfl_xor(rc, 1);
            cc += __shfl_xor(cc, 1);
            if (!half) {
                invd_g[pl] = 1.0f / (float)(rc + 1);
                out[(size_t)NP * DD + pl] = (rc + cc == 0) ? 1.0f : 0.0f;
            }
        } else if (t < 46400) {                // deprel bf16 pack (2000 quads)
            int i = t - 44400;
            float4 v = ((const float4*)dep)[i];
            depp_g[i] = make_uint2(pk2(v.x, v.y), pk2(v.z, v.w));
        } else if (t < 126400) {               // adj byte-pack: all 3200 rows x 25 quads
            int i = t - 46400;
            int4 a = ((const int4*)adj)[i];
            adjp_g[i] = (unsigned)a.x | ((unsigned)a.y << 8) |
                        ((unsigned)a.z << 16) | ((unsigned)a.w << 24);
        }
    }

    grid_barrier(bar);

    // ================= Phase B: embed gather + proj GEMV (blocks 0..199) =================
    if (bid < 200) {
        float* es = (float*)smem;                    // 16*360 f32 = 23040 B
        float4* red = (float4*)(smem + 23040);       // 2 clusters * 2 slots * 400 = 25600 B
        int pbase = bid * 16;
        float2* es2 = (float2*)es;
        for (int idx = tid; idx < 16 * 180; idx += NTHR) {
            int p = idx / 180, j2 = idx % 180;
            int gp = pbase + p;
            float2 v;
            if (j2 < 150)      v = ((const float2*)emb)[(size_t)words[gp] * 150 + j2];
            else if (j2 < 165) v = ((const float2*)pose)[pos[gp] * 15 + (j2 - 150)];
            else               v = ((const float2*)nere)[ner[gp] * 15 + (j2 - 165)];
            es2[idx] = v;
        }
        __syncthreads();

        int lane = tid & 63, wv = tid >> 6;
        int c = wv >> 2, w4 = wv & 3;
        bool act = lane < 50;
        int oq = act ? lane : 49;
        int kq0 = w4 * 24;
        int kqn = (w4 < 3) ? 24 : 18;
        const float4* wt4 = (const float4*)wpT;
        const float4* es4 = (const float4*)es;
        float4 a[8];
        #pragma unroll
        for (int p = 0; p < 8; ++p) a[p] = make_float4(0.f, 0.f, 0.f, 0.f);
        for (int k = 0; k < kqn; ++k) {
            int kq = kq0 + k;
            float4 w0 = wt4[(size_t)(4 * kq + 0) * 50 + oq];
            float4 w1 = wt4[(size_t)(4 * kq + 1) * 50 + oq];
            float4 w2 = wt4[(size_t)(4 * kq + 2) * 50 + oq];
            float4 w3 = wt4[(size_t)(4 * kq + 3) * 50 + oq];
            #pragma unroll
            for (int p = 0; p < 8; ++p) {
                float4 s = es4[(c * 8 + p) * 90 + kq];   // wave-uniform broadcast
                fma4(a[p], w0, s.x); fma4(a[p], w1, s.y);
                fma4(a[p], w2, s.z); fma4(a[p], w3, s.w);
            }
        }
        float4* redc = red + c * 800;
        if (w4 >= 2 && act) {
            #pragma unroll
            for (int p = 0; p < 8; ++p) redc[(w4 - 2) * 400 + p * 50 + oq] = a[p];
        }
        __syncthreads();
        if (w4 < 2 && act) {
            #pragma unroll
            for (int p = 0; p < 8; ++p) {
                float4 r = redc[w4 * 400 + p * 50 + oq];
                r.x += a[p].x; r.y += a[p].y; r.z += a[p].z; r.w += a[p].w;
                redc[w4 * 400 + p * 50 + oq] = r;
            }
        }
        __syncthreads();
        for (int t2 = tid; t2 < 800; t2 += NTHR) {
            int pp = t2 / 50, oq2 = t2 % 50;
            float4* rc2 = red + (pp >> 3) * 800;
            float4 v0 = rc2[(pp & 7) * 50 + oq2];
            float4 v1 = rc2[400 + (pp & 7) * 50 + oq2];
            float4 bb = ((const float4*)bp)[oq2];
            float4 v;
            v.x = v0.x + v1.x + bb.x; v.y = v0.y + v1.y + bb.y;
            v.z = v0.z + v1.z + bb.z; v.w = v0.w + v1.w + bb.w;
            ((float4*)xA)[(size_t)(pbase + pp) * 50 + oq2] = v;
        }
    }

    // ================= Phases C/D: the two GCN layers =================
    uint2* deps_b = (uint2*)smem;                 // 16000 B
    unsigned* adjp = (unsigned*)(smem + 16000);   //  1300 B
    float4* Sh = (float4*)(smem + 17312);         // 20800 B
    float4* Sfin = (float4*)(smem + 38112);       // 10400 B
    int b = bid >> 3, tile = bid & 7;
    int l0 = tile * LT;
    int lcnt = min(LT, LL - l0);
    int lane = tid & 63, wv = tid >> 6;
    int lg = wv & 3, mh = wv >> 2;
    bool act = lane < 50;
    int dq = lane;

    for (int layer = 0; layer < 2; ++layer) {
        grid_barrier(bar);
        const float* xin = layer ? xB : xA;
        float* xout = layer ? out : xB;
        const float* wt = layer ? w1T : w0T;
        const float* bias = layer ? b1 : b0;
        const float4* x4 = (const float4*)xin;

        if (layer == 0) {   // stage layer-invariant LDS once (persists across barrier)
            for (int i = tid; i < 2000; i += NTHR) deps_b[i] = depp_g[i];
            for (int i = tid; i < lcnt * 25; i += NTHR)
                adjp[i] = adjp_g[(b * LL + l0) * 25 + i];
        }
        __syncthreads();

        // ---- Ax over m-half ----
        float4 acc[4];
        #pragma unroll
        for (int i = 0; i < 4; ++i) acc[i] = make_float4(0.f, 0.f, 0.f, 0.f);
        if (act) {
            int mg0 = mh ? 13 : 0, mg1 = mh ? 25 : 13;
            for (int mg = mg0; mg < mg1; ++mg) {
                unsigned ap[4];
                #pragma unroll
                for (int i = 0; i < 4; ++i) {
                    int li = lg + 4 * i;
                    ap[i] = (li < lcnt) ? adjp[li * 25 + mg] : 0u;
                }
                #pragma unroll
                for (int mm = 0; mm < 4; ++mm) {
                    float4 xv = x4[(size_t)(b * LL + 4 * mg + mm) * 50 + dq];
                    #pragma unroll
                    for (int i = 0; i < 4; ++i) {
                        unsigned r = (ap[i] >> (8 * mm)) & 0xffu;
                        uint2 dv = deps_b[r * 50 + dq];
                        acc[i].x = fmaf(lo16(dv.x), xv.x, acc[i].x);
                        acc[i].y = fmaf(hi16(dv.x), xv.y, acc[i].y);
                        acc[i].z = fmaf(lo16(dv.y), xv.z, acc[i].z);
                        acc[i].w = fmaf(hi16(dv.y), xv.w, acc[i].w);
                    }
                }
            }
            #pragma unroll
            for (int i = 0; i < 4; ++i) {
                int li = lg + 4 * i;
                if (li < lcnt) Sh[mh * 650 + li * 50 + dq] = acc[i];
            }
        }
        __syncthreads();

        // ---- reduce halves + fp32 residual ----
        for (int t2 = tid; t2 < 650; t2 += NTHR) {
            int li = t2 / 50;
            if (li < lcnt) {
                float4 s0 = Sh[t2], s1 = Sh[650 + t2];
                float4 xr = x4[(size_t)(b * LL + l0 + li) * 50 + (t2 % 50)];
                float4 s;
                s.x = s0.x + s1.x + xr.x; s.y = s0.y + s1.y + xr.y;
                s.z = s0.z + s1.z + xr.z; s.w = s0.w + s1.w + xr.w;
                Sfin[t2] = s;
            }
        }
        __syncthreads();

        // ---- GEMV over k-half ----
        const float4* wt4 = (const float4*)wt;
        int oq = act ? lane : 49;
        float4 ba[4];
        #pragma unroll
        for (int i = 0; i < 4; ++i) ba[i] = make_float4(0.f, 0.f, 0.f, 0.f);
        for (int k = 0; k < 25; ++k) {
            int kq = mh * 25 + k;
            float4 w0 = wt4[(size_t)(4 * kq + 0) * 50 + oq];
            float4 w1 = wt4[(size_t)(4 * kq + 1) * 50 + oq];
            float4 w2 = wt4[(size_t)(4 * kq + 2) * 50 + oq];
            float4 w3 = wt4[(size_t)(4 * kq + 3) * 50 + oq];
            #pragma unroll
            for (int i = 0; i < 4; ++i) {
                int li = lg + 4 * i;
                int lic = li < lcnt ? li : lcnt - 1;
                float4 s = Sfin[lic * 50 + kq];   // wave-uniform broadcast
                fma4(ba[i], w0, s.x); fma4(ba[i], w1, s.y);
                fma4(ba[i], w2, s.z); fma4(ba[i], w3, s.w);
            }
        }
        if (act) {
            #pragma unroll
            for (int i = 0; i < 4; ++i) {
                int li = lg + 4 * i;
                if (li < lcnt) Sh[mh * 650 + li * 50 + oq] = ba[i];
            }
        }
        __syncthreads();

        for (int t2 = tid; t2 < 650; t2 += NTHR) {
            int li = t2 / 50, oq2 = t2 % 50;
            if (li < lcnt) {
                float4 v0 = Sh[t2], v1 = Sh[650 + t2];
                float4 bb = ((const float4*)bias)[oq2];
                int p = b * LL + l0 + li;
                float sc = invd_g[p];
                float4 v;
                v.x = fmaxf((v0.x + v1.x + 2.f * bb.x) * sc, 0.f);
                v.y = fmaxf((v0.y + v1.y + 2.f * bb.y) * sc, 0.f);
                v.z = fmaxf((v0.z + v1.z + 2.f * bb.z) * sc, 0.f);
                v.w = fmaxf((v0.w + v1.w + 2.f * bb.w) * sc, 0.f);
                ((float4*)xout)[(size_t)p * 50 + oq2] = v;
            }
        }
        __syncthreads();   // protect Sh before next layer reuses smem
    }
}

extern "C" void kernel_launch(void* const* d_in, const int* in_sizes, int n_in,
                              void* d_out, int out_size, void* d_ws, size_t ws_size,
                              hipStream_t stream) {
    const int*   adj   = (const int*)d_in[0];
    const int*   words = (const int*)d_in[1];
    const int*   pos   = (const int*)d_in[2];
    const int*   ner   = (const int*)d_in[3];
    const float* emb   = (const float*)d_in[4];
    const float* pose  = (const float*)d_in[5];
    const float* nere  = (const float*)d_in[6];
    const float* dep   = (const float*)d_in[7];
    const float* Wp    = (const float*)d_in[8];
    const float* bp    = (const float*)d_in[9];
    const float* W0    = (const float*)d_in[10];
    const float* b0    = (const float*)d_in[11];
    const float* W1    = (const float*)d_in[12];
    const float* b1    = (const float*)d_in[13];
    float* out = (float*)d_out;
    float* ws  = (float*)d_ws;

    hipMemsetAsync(ws + OFF_BAR, 0, 8, stream);   // reset grid barrier
    fused_kernel<<<NBLK, NTHR, 0, stream>>>(adj, words, pos, ner, emb, pose, nere,
                                            dep, Wp, bp, W0, b0, W1, b1, ws, out);
}

// Round 6
// 74.094 us; speedup vs baseline: 3.4643x; 1.8586x over previous
//
#include <hip/hip_runtime.h>
#include <hip/hip_bf16.h>

#define BB 32
#define LL 100
#define DD 200      // MEM
#define KIN 360
#define NP (BB*LL)  // 3200
#define RNUM 40
#define LT 13
#define NT 8        // l-tiles of 13 (last = 9)

__device__ __forceinline__ void fma4(float4& a, const float4& w, float s) {
    a.x = fmaf(w.x, s, a.x);
    a.y = fmaf(w.y, s, a.y);
    a.z = fmaf(w.z, s, a.z);
    a.w = fmaf(w.w, s, a.w);
}
// RTNE f32 -> bf16
__device__ __forceinline__ unsigned bf16rn(float f) {
    unsigned u = __float_as_uint(f);
    return (u + 0x7fffu + ((u >> 16) & 1u)) >> 16;
}
__device__ __forceinline__ unsigned pk2(float a, float b) {
    return bf16rn(a) | (bf16rn(b) << 16);
}
__device__ __forceinline__ float lo16(unsigned u) { return __uint_as_float(u << 16); }
__device__ __forceinline__ float hi16(unsigned u) { return __uint_as_float(u & 0xffff0000u); }

// ---------------- kernel A: prep (invd, mask) + weight transposes ----------------
__global__ __launch_bounds__(256) void prep_transpose_kernel(
        const int* __restrict__ adj,
        const float* __restrict__ Wp, const float* __restrict__ W0, const float* __restrict__ W1,
        float* __restrict__ WpT, float* __restrict__ W0T, float* __restrict__ W1T,
        float* __restrict__ invd, float* __restrict__ mask_out) {
    int bid = blockIdx.x, tid = threadIdx.x;
    if (bid < 25) {
        int t = bid * 256 + tid;          // < 6400 exactly
        int half = t & 1;
        int pl = t >> 1;                  // (b,l) id 0..3199
        int b = pl / LL, l = pl % LL;
        const int4* row = (const int4*)(adj + (size_t)pl * LL);
        int q0 = half ? 13 : 0, q1 = half ? 25 : 13;
        int rc = 0;
        for (int i = q0; i < q1; ++i) {
            int4 a = row[i];
            rc += (a.x != 0) + (a.y != 0) + (a.z != 0) + (a.w != 0);
        }
        const int* base = adj + (size_t)b * LL * LL + l;
        int cc = 0;
        for (int m = half * 50; m < half * 50 + 50; ++m) cc += (base[(size_t)m * LL] != 0);
        rc += __shfl_xor(rc, 1);
        cc += __shfl_xor(cc, 1);
        if (!half) {
            invd[pl] = 1.0f / (float)(rc + 1);
            mask_out[pl] = (rc + cc == 0) ? 1.0f : 0.0f;
        }
    } else {
        int i = (bid - 25) * 256 + tid;   // output quad index
        if (i < 18000) {                  // WpT: [360][200]
            int k = i / 50, o = (i % 50) * 4;
            float4 v;
            v.x = Wp[(size_t)(o + 0) * KIN + k];
            v.y = Wp[(size_t)(o + 1) * KIN + k];
            v.z = Wp[(size_t)(o + 2) * KIN + k];
            v.w = Wp[(size_t)(o + 3) * KIN + k];
            ((float4*)WpT)[i] = v;
        } else if (i < 28000) {           // W0T: [200][200]
            int q = i - 18000;
            int k = q / 50, o = (q % 50) * 4;
            float4 v;
            v.x = W0[(size_t)(o + 0) * DD + k];
            v.y = W0[(size_t)(o + 1) * DD + k];
            v.z = W0[(size_t)(o + 2) * DD + k];
            v.w = W0[(size_t)(o + 3) * DD + k];
            ((float4*)W0T)[q] = v;
        } else if (i < 38000) {           // W1T
            int q = i - 28000;
            int k = q / 50, o = (q % 50) * 4;
            float4 v;
            v.x = W1[(size_t)(o + 0) * DD + k];
            v.y = W1[(size_t)(o + 1) * DD + k];
            v.z = W1[(size_t)(o + 2) * DD + k];
            v.w = W1[(size_t)(o + 3) * DD + k];
            ((float4*)W1T)[q] = v;
        }
    }
}

// ---------------- kernel B: embed gather + proj GEMV, 4-way K-split, pipelined ----------------
// 400 blocks x 256 threads. Block = 8 positions; wave w = K-chunk w (quads {0..23,
// 24..47, 48..71, 72..89}); double-buffered weight-pair prefetch; LDS reduce.
__global__ __launch_bounds__(256) void embed_gemv_kernel(
        const int* __restrict__ words, const int* __restrict__ pos, const int* __restrict__ ner,
        const float* __restrict__ emb, const float* __restrict__ pose, const float* __restrict__ nere,
        const float* __restrict__ wpt, const float* __restrict__ bp,
        float* __restrict__ xA) {
    __shared__ float es[8 * KIN];        // 11520 B
    __shared__ float4 red[4 * 8 * 50];   // 25600 B
    int tid = threadIdx.x;
    int pbase = blockIdx.x * 8;

    float2* es2 = (float2*)es;
    for (int idx = tid; idx < 8 * 180; idx += 256) {
        int p = idx / 180, j2 = idx % 180;
        int gp = pbase + p;
        float2 v;
        if (j2 < 150)      v = ((const float2*)emb)[(size_t)words[gp] * 150 + j2];
        else if (j2 < 165) v = ((const float2*)pose)[pos[gp] * 15 + (j2 - 150)];
        else               v = ((const float2*)nere)[ner[gp] * 15 + (j2 - 165)];
        es2[idx] = v;
    }
    __syncthreads();

    int lane = tid & 63, w = tid >> 6;
    bool act = lane < 50;
    int oq = act ? lane : 49;
    int kq0 = w * 24;
    int npair = (w < 3) ? 12 : 9;        // 24 or 18 quads, all even
    int kqlast = kq0 + 2 * npair - 1;
    const float4* wt4 = (const float4*)wpt;
    const float4* es4 = (const float4*)es;

    float4 a[8];
    #pragma unroll
    for (int p = 0; p < 8; ++p) a[p] = make_float4(0.f, 0.f, 0.f, 0.f);

    float4 wc[8], wn[8];
    #pragma unroll
    for (int q = 0; q < 2; ++q)
        #pragma unroll
        for (int j = 0; j < 4; ++j)
            wc[q * 4 + j] = wt4[(size_t)(4 * (kq0 + q) + j) * 50 + oq];

    for (int pr = 0; pr < npair; ++pr) {
        // prefetch next pair (clamped dummy on last iteration)
        int nb = kq0 + 2 * pr + 2;
        int nbA = nb <= kqlast ? nb : kq0;
        int nbB = nb + 1 <= kqlast ? nb + 1 : kq0;
        #pragma unroll
        for (int j = 0; j < 4; ++j) wn[j]     = wt4[(size_t)(4 * nbA + j) * 50 + oq];
        #pragma unroll
        for (int j = 0; j < 4; ++j) wn[4 + j] = wt4[(size_t)(4 * nbB + j) * 50 + oq];
        // compute current pair
        #pragma unroll
        for (int q = 0; q < 2; ++q) {
            int kq = kq0 + 2 * pr + q;
            #pragma unroll
            for (int p = 0; p < 8; ++p) {
                float4 s = es4[p * 90 + kq];   // wave-uniform broadcast
                fma4(a[p], wc[q * 4 + 0], s.x); fma4(a[p], wc[q * 4 + 1], s.y);
                fma4(a[p], wc[q * 4 + 2], s.z); fma4(a[p], wc[q * 4 + 3], s.w);
            }
        }
        #pragma unroll
        for (int j = 0; j < 8; ++j) wc[j] = wn[j];
    }

    if (act) {
        #pragma unroll
        for (int p = 0; p < 8; ++p) red[w * 400 + p * 50 + oq] = a[p];
    }
    __syncthreads();
    for (int t = tid; t < 400; t += 256) {
        int oq2 = t % 50;
        float4 v0 = red[t], v1 = red[400 + t], v2 = red[800 + t], v3 = red[1200 + t];
        float4 bb = ((const float4*)bp)[oq2];
        float4 v;
        v.x = v0.x + v1.x + v2.x + v3.x + bb.x;
        v.y = v0.y + v1.y + v2.y + v3.y + bb.y;
        v.z = v0.z + v1.z + v2.z + v3.z + bb.z;
        v.w = v0.w + v1.w + v2.w + v3.w + bb.w;
        ((float4*)xA)[(size_t)(pbase + t / 50) * 50 + oq2] = v;
    }
}

// ---------------- kernel C: fused layer, 512 threads, pipelined ----------------
__global__ __launch_bounds__(512) void layer_kernel(
        const float* __restrict__ x, const int* __restrict__ adj,
        const float* __restrict__ deprel, const float* __restrict__ wt,
        const float* __restrict__ bias, const float* __restrict__ invd,
        float* __restrict__ out) {
    __shared__ uint2 deps_b[RNUM * 50];   // 16000 B
    __shared__ unsigned adjp[LT * 25];    //  1300 B
    __shared__ float4 Sh[2 * 650];        // 20800 B
    __shared__ float4 Sfin[650];          // 10400 B
    int b = blockIdx.y, tile = blockIdx.x;
    int l0 = tile * LT;
    int lcnt = min(LT, LL - l0);
    int tid = threadIdx.x;
    const float4* x4 = (const float4*)x;

    for (int i = tid; i < RNUM * 50; i += 512) {
        float4 v = ((const float4*)deprel)[i];
        deps_b[i] = make_uint2(pk2(v.x, v.y), pk2(v.z, v.w));
    }
    for (int i = tid; i < lcnt * 25; i += 512) {
        int li = i / 25, mg = i % 25;
        int4 a = ((const int4*)(adj + (size_t)(b * LL + l0 + li) * LL))[mg];
        adjp[i] = (unsigned)a.x | ((unsigned)a.y << 8) | ((unsigned)a.z << 16) | ((unsigned)a.w << 24);
    }
    __syncthreads();

    int lane = tid & 63, w = tid >> 6;   // 8 waves
    int lg = w & 3, mh = w >> 2;
    bool act = lane < 50;
    int dq = lane;

    // ---- Ax over m-half, one-mg-ahead x prefetch ----
    float4 acc[4];
    #pragma unroll
    for (int i = 0; i < 4; ++i) acc[i] = make_float4(0.f, 0.f, 0.f, 0.f);
    if (act) {
        int mg0 = mh ? 13 : 0, mg1 = mh ? 25 : 13;
        float4 xc[4], xn[4];
        #pragma unroll
        for (int mm = 0; mm < 4; ++mm)
            xc[mm] = x4[(size_t)(b * LL + 4 * mg0 + mm) * 50 + dq];
        for (int mg = mg0; mg < mg1; ++mg) {
            int mgn = (mg + 1 < mg1) ? mg + 1 : mg;   // dummy reload on last iter
            #pragma unroll
            for (int mm = 0; mm < 4; ++mm)
                xn[mm] = x4[(size_t)(b * LL + 4 * mgn + mm) * 50 + dq];
            unsigned ap[4];
            #pragma unroll
            for (int i = 0; i < 4; ++i) {
                int li = lg + 4 * i;
                ap[i] = (li < lcnt) ? adjp[li * 25 + mg] : 0u;
            }
            #pragma unroll
            for (int mm = 0; mm < 4; ++mm) {
                #pragma unroll
                for (int i = 0; i < 4; ++i) {
                    unsigned r = (ap[i] >> (8 * mm)) & 0xffu;
                    uint2 dv = deps_b[r * 50 + dq];
                    acc[i].x = fmaf(lo16(dv.x), xc[mm].x, acc[i].x);
                    acc[i].y = fmaf(hi16(dv.x), xc[mm].y, acc[i].y);
                    acc[i].z = fmaf(lo16(dv.y), xc[mm].z, acc[i].z);
                    acc[i].w = fmaf(hi16(dv.y), xc[mm].w, acc[i].w);
                }
            }
            #pragma unroll
            for (int mm = 0; mm < 4; ++mm) xc[mm] = xn[mm];
        }
        #pragma unroll
        for (int i = 0; i < 4; ++i) {
            int li = lg + 4 * i;
            if (li < lcnt) Sh[mh * 650 + li * 50 + dq] = acc[i];
        }
    }
    __syncthreads();

    // ---- reduce halves + fp32 residual ----
    for (int t2 = tid; t2 < 650; t2 += 512) {
        int li = t2 / 50;
        if (li < lcnt) {
            float4 s0 = Sh[t2], s1 = Sh[650 + t2];
            float4 xr = x4[(size_t)(b * LL + l0 + li) * 50 + (t2 % 50)];
            float4 s;
            s.x = s0.x + s1.x + xr.x; s.y = s0.y + s1.y + xr.y;
            s.z = s0.z + s1.z + xr.z; s.w = s0.w + s1.w + xr.w;
            Sfin[t2] = s;
        }
    }
    __syncthreads();

    // ---- GEMV over k-half (25 quads = 12 pairs + 1 tail), pipelined ----
    const float4* wt4 = (const float4*)wt;
    int oq = act ? lane : 49;
    int kq0 = mh * 25;
    float4 ba[4];
    #pragma unroll
    for (int i = 0; i < 4; ++i) ba[i] = make_float4(0.f, 0.f, 0.f, 0.f);

    float4 wc[8], wn[8];
    #pragma unroll
    for (int q = 0; q < 2; ++q)
        #pragma unroll
        for (int j = 0; j < 4; ++j)
            wc[q * 4 + j] = wt4[(size_t)(4 * (kq0 + q) + j) * 50 + oq];

    int lic[4];
    #pragma unroll
    for (int i = 0; i < 4; ++i) {
        int li = lg + 4 * i;
        lic[i] = li < lcnt ? li : lcnt - 1;
    }

    for (int pr = 0; pr < 12; ++pr) {
        int nb = kq0 + 2 * pr + 2;
        int nbB = (nb + 1 <= kq0 + 24) ? nb + 1 : kq0;   // clamp dummy
        #pragma unroll
        for (int j = 0; j < 4; ++j) wn[j]     = wt4[(size_t)(4 * nb + j) * 50 + oq];
        #pragma unroll
        for (int j = 0; j < 4; ++j) wn[4 + j] = wt4[(size_t)(4 * nbB + j) * 50 + oq];
        #pragma unroll
        for (int q = 0; q < 2; ++q) {
            int kq = kq0 + 2 * pr + q;
            #pragma unroll
            for (int i = 0; i < 4; ++i) {
                float4 s = Sfin[lic[i] * 50 + kq];   // wave-uniform broadcast
                fma4(ba[i], wc[q * 4 + 0], s.x); fma4(ba[i], wc[q * 4 + 1], s.y);
                fma4(ba[i], wc[q * 4 + 2], s.z); fma4(ba[i], wc[q * 4 + 3], s.w);
            }
        }
        #pragma unroll
        for (int j = 0; j < 8; ++j) wc[j] = wn[j];
    }
    {   // tail quad kq0+24 (sits in wc[0..3])
        int kq = kq0 + 24;
        #pragma unroll
        for (int i = 0; i < 4; ++i) {
            float4 s = Sfin[lic[i] * 50 + kq];
            fma4(ba[i], wc[0], s.x); fma4(ba[i], wc[1], s.y);
            fma4(ba[i], wc[2], s.z); fma4(ba[i], wc[3], s.w);
        }
    }

    if (act) {
        #pragma unroll
        for (int i = 0; i < 4; ++i) {
            int li = lg + 4 * i;
            if (li < lcnt) Sh[mh * 650 + li * 50 + oq] = ba[i];
        }
    }
    __syncthreads();

    for (int t2 = tid; t2 < 650; t2 += 512) {
        int li = t2 / 50, oq2 = t2 % 50;
        if (li < lcnt) {
            float4 v0 = Sh[t2], v1 = Sh[650 + t2];
            float4 bb = ((const float4*)bias)[oq2];
            int p = b * LL + l0 + li;
            float sc = invd[p];
            float4 v;
            v.x = fmaxf((v0.x + v1.x + 2.f * bb.x) * sc, 0.f);
            v.y = fmaxf((v0.y + v1.y + 2.f * bb.y) * sc, 0.f);
            v.z = fmaxf((v0.z + v1.z + 2.f * bb.z) * sc, 0.f);
            v.w = fmaxf((v0.w + v1.w + 2.f * bb.w) * sc, 0.f);
            ((float4*)out)[(size_t)p * 50 + oq2] = v;
        }
    }
}

extern "C" void kernel_launch(void* const* d_in, const int* in_sizes, int n_in,
                              void* d_out, int out_size, void* d_ws, size_t ws_size,
                              hipStream_t stream) {
    const int*   adj   = (const int*)d_in[0];
    const int*   words = (const int*)d_in[1];
    const int*   pos   = (const int*)d_in[2];
    const int*   ner   = (const int*)d_in[3];
    const float* emb   = (const float*)d_in[4];
    const float* pose  = (const float*)d_in[5];
    const float* nere  = (const float*)d_in[6];
    const float* dep   = (const float*)d_in[7];
    const float* Wp    = (const float*)d_in[8];
    const float* bp    = (const float*)d_in[9];
    const float* W0    = (const float*)d_in[10];
    const float* b0    = (const float*)d_in[11];
    const float* W1    = (const float*)d_in[12];
    const float* b1    = (const float*)d_in[13];
    float* out = (float*)d_out;
    float* ws  = (float*)d_ws;

    float* xA   = ws;                // 640,000
    float* xB   = ws + 640000;       // 640,000
    float* WpT  = ws + 1280000;      //  72,000
    float* W0T  = ws + 1352000;      //  40,000
    float* W1T  = ws + 1392000;      //  40,000
    float* invd = ws + 1432000;      //   3,200

    prep_transpose_kernel<<<25 + 149, 256, 0, stream>>>(adj, Wp, W0, W1, WpT, W0T, W1T,
                                                        invd, out + (size_t)NP * DD);
    embed_gemv_kernel<<<NP / 8, 256, 0, stream>>>(words, pos, ner, emb, pose, nere,
                                                  WpT, bp, xA);
    layer_kernel<<<dim3(NT, BB), 512, 0, stream>>>(xA, adj, dep, W0T, b0, invd, xB);
    layer_kernel<<<dim3(NT, BB), 512, 0, stream>>>(xB, adj, dep, W1T, b1, invd, out);
}

// Round 7
// 69.800 us; speedup vs baseline: 3.6774x; 1.0615x over previous
//
#include <hip/hip_runtime.h>
#include <hip/hip_bf16.h>

#define BB 32
#define LL 100
#define DD 200      // MEM
#define KIN 360
#define NP (BB*LL)  // 3200
#define RNUM 40
#define LT 13
#define NT 8        // l-tiles of 13 (last = 9)

__device__ __forceinline__ void fma4(float4& a, const float4& w, float s) {
    a.x = fmaf(w.x, s, a.x);
    a.y = fmaf(w.y, s, a.y);
    a.z = fmaf(w.z, s, a.z);
    a.w = fmaf(w.w, s, a.w);
}
// RTNE f32 -> bf16
__device__ __forceinline__ unsigned bf16rn(float f) {
    unsigned u = __float_as_uint(f);
    return (u + 0x7fffu + ((u >> 16) & 1u)) >> 16;
}
__device__ __forceinline__ unsigned pk2(float a, float b) {
    return bf16rn(a) | (bf16rn(b) << 16);
}
__device__ __forceinline__ float lo16(unsigned u) { return __uint_as_float(u << 16); }
__device__ __forceinline__ float hi16(unsigned u) { return __uint_as_float(u & 0xffff0000u); }

// ---------------- kernel A: prep (invd, mask) + weight transposes ----------------
__global__ __launch_bounds__(256) void prep_transpose_kernel(
        const int* __restrict__ adj,
        const float* __restrict__ Wp, const float* __restrict__ W0, const float* __restrict__ W1,
        float* __restrict__ WpT, float* __restrict__ W0T, float* __restrict__ W1T,
        float* __restrict__ invd, float* __restrict__ mask_out) {
    int bid = blockIdx.x, tid = threadIdx.x;
    if (bid < 25) {
        int t = bid * 256 + tid;          // < 6400 exactly
        int half = t & 1;
        int pl = t >> 1;                  // (b,l) id 0..3199
        int b = pl / LL, l = pl % LL;
        const int4* row = (const int4*)(adj + (size_t)pl * LL);
        int q0 = half ? 13 : 0, q1 = half ? 25 : 13;
        int rc = 0;
        for (int i = q0; i < q1; ++i) {
            int4 a = row[i];
            rc += (a.x != 0) + (a.y != 0) + (a.z != 0) + (a.w != 0);
        }
        const int* base = adj + (size_t)b * LL * LL + l;
        int cc = 0;
        for (int m = half * 50; m < half * 50 + 50; ++m) cc += (base[(size_t)m * LL] != 0);
        rc += __shfl_xor(rc, 1);
        cc += __shfl_xor(cc, 1);
        if (!half) {
            invd[pl] = 1.0f / (float)(rc + 1);
            mask_out[pl] = (rc + cc == 0) ? 1.0f : 0.0f;
        }
    } else {
        int i = (bid - 25) * 256 + tid;   // output quad index
        if (i < 18000) {                  // WpT: [360][200]
            int k = i / 50, o = (i % 50) * 4;
            float4 v;
            v.x = Wp[(size_t)(o + 0) * KIN + k];
            v.y = Wp[(size_t)(o + 1) * KIN + k];
            v.z = Wp[(size_t)(o + 2) * KIN + k];
            v.w = Wp[(size_t)(o + 3) * KIN + k];
            ((float4*)WpT)[i] = v;
        } else if (i < 28000) {           // W0T: [200][200]
            int q = i - 18000;
            int k = q / 50, o = (q % 50) * 4;
            float4 v;
            v.x = W0[(size_t)(o + 0) * DD + k];
            v.y = W0[(size_t)(o + 1) * DD + k];
            v.z = W0[(size_t)(o + 2) * DD + k];
            v.w = W0[(size_t)(o + 3) * DD + k];
            ((float4*)W0T)[q] = v;
        } else if (i < 38000) {           // W1T
            int q = i - 28000;
            int k = q / 50, o = (q % 50) * 4;
            float4 v;
            v.x = W1[(size_t)(o + 0) * DD + k];
            v.y = W1[(size_t)(o + 1) * DD + k];
            v.z = W1[(size_t)(o + 2) * DD + k];
            v.w = W1[(size_t)(o + 3) * DD + k];
            ((float4*)W1T)[q] = v;
        }
    }
}

// ---------------- kernel B: embed gather + proj GEMV, 8-way K-split, pipelined ----------------
// 400 blocks x 512 threads. Block = 8 positions; wave w = K-chunk (quads: 12,12,12,12,12,10,10,10);
// 8-slot LDS reduce.
__global__ __launch_bounds__(512, 4) void embed_gemv_kernel(
        const int* __restrict__ words, const int* __restrict__ pos, const int* __restrict__ ner,
        const float* __restrict__ emb, const float* __restrict__ pose, const float* __restrict__ nere,
        const float* __restrict__ wpt, const float* __restrict__ bp,
        float* __restrict__ xA) {
    __shared__ float es[8 * KIN];        // 11520 B
    __shared__ float4 red[8 * 8 * 50];   // 51200 B  (8 slots)
    int tid = threadIdx.x;
    int pbase = blockIdx.x * 8;

    float2* es2 = (float2*)es;
    for (int idx = tid; idx < 8 * 180; idx += 512) {
        int p = idx / 180, j2 = idx % 180;
        int gp = pbase + p;
        float2 v;
        if (j2 < 150)      v = ((const float2*)emb)[(size_t)words[gp] * 150 + j2];
        else if (j2 < 165) v = ((const float2*)pose)[pos[gp] * 15 + (j2 - 150)];
        else               v = ((const float2*)nere)[ner[gp] * 15 + (j2 - 165)];
        es2[idx] = v;
    }
    __syncthreads();

    int lane = tid & 63, w = tid >> 6;   // 8 waves
    bool act = lane < 50;
    int oq = act ? lane : 49;
    int kq0 = (w < 5) ? 12 * w : 60 + 10 * (w - 5);
    int npair = (w < 5) ? 6 : 5;         // all chunks even
    int kqlast = kq0 + 2 * npair - 1;
    const float4* wt4 = (const float4*)wpt;
    const float4* es4 = (const float4*)es;

    float4 a[8];
    #pragma unroll
    for (int p = 0; p < 8; ++p) a[p] = make_float4(0.f, 0.f, 0.f, 0.f);

    float4 wc[8], wn[8];
    #pragma unroll
    for (int q = 0; q < 2; ++q)
        #pragma unroll
        for (int j = 0; j < 4; ++j)
            wc[q * 4 + j] = wt4[(size_t)(4 * (kq0 + q) + j) * 50 + oq];

    for (int pr = 0; pr < npair; ++pr) {
        int nb = kq0 + 2 * pr + 2;
        int nbA = nb <= kqlast ? nb : kq0;
        int nbB = nb + 1 <= kqlast ? nb + 1 : kq0;
        #pragma unroll
        for (int j = 0; j < 4; ++j) wn[j]     = wt4[(size_t)(4 * nbA + j) * 50 + oq];
        #pragma unroll
        for (int j = 0; j < 4; ++j) wn[4 + j] = wt4[(size_t)(4 * nbB + j) * 50 + oq];
        #pragma unroll
        for (int q = 0; q < 2; ++q) {
            int kq = kq0 + 2 * pr + q;
            #pragma unroll
            for (int p = 0; p < 8; ++p) {
                float4 s = es4[p * 90 + kq];   // wave-uniform broadcast
                fma4(a[p], wc[q * 4 + 0], s.x); fma4(a[p], wc[q * 4 + 1], s.y);
                fma4(a[p], wc[q * 4 + 2], s.z); fma4(a[p], wc[q * 4 + 3], s.w);
            }
        }
        #pragma unroll
        for (int j = 0; j < 8; ++j) wc[j] = wn[j];
    }

    if (act) {
        #pragma unroll
        for (int p = 0; p < 8; ++p) red[w * 400 + p * 50 + oq] = a[p];
    }
    __syncthreads();
    for (int t = tid; t < 400; t += 512) {
        int oq2 = t % 50;
        float4 v = ((const float4*)bp)[oq2];
        #pragma unroll
        for (int s = 0; s < 8; ++s) {
            float4 r = red[s * 400 + t];
            v.x += r.x; v.y += r.y; v.z += r.z; v.w += r.w;
        }
        ((float4*)xA)[(size_t)(pbase + t / 50) * 50 + oq2] = v;
    }
}

// ---------------- kernel C: fused layer, 1024 threads / 16 waves ----------------
// Waves: lg = w&3 (l-group: l = lg+4i), sq = w>>2 (m-quarter for Ax, k-quarter for GEMV).
__global__ __launch_bounds__(1024, 4) void layer_kernel(
        const float* __restrict__ x, const int* __restrict__ adj,
        const float* __restrict__ deprel, const float* __restrict__ wt,
        const float* __restrict__ bias, const float* __restrict__ invd,
        float* __restrict__ out) {
    __shared__ alignas(16) char smem[58912];
    uint2* deps_b = (uint2*)smem;                 // [0, 16000)       Ax only
    unsigned* adjp = (unsigned*)(smem + 16000);   // [16000, 17300)   Ax only
    float4* Sh = (float4*)(smem + 17312);         // [17312, 58912)   4 slots x 650
    float4* Sfin = (float4*)smem;                 // [0, 10400)       overlays deps (dead)

    int b = blockIdx.y, tile = blockIdx.x;
    int l0 = tile * LT;
    int lcnt = min(LT, LL - l0);
    int tid = threadIdx.x;
    const float4* x4 = (const float4*)x;

    for (int i = tid; i < RNUM * 50; i += 1024) {
        float4 v = ((const float4*)deprel)[i];
        deps_b[i] = make_uint2(pk2(v.x, v.y), pk2(v.z, v.w));
    }
    for (int i = tid; i < lcnt * 25; i += 1024) {
        int li = i / 25, mg = i % 25;
        int4 a = ((const int4*)(adj + (size_t)(b * LL + l0 + li) * LL))[mg];
        adjp[i] = (unsigned)a.x | ((unsigned)a.y << 8) | ((unsigned)a.z << 16) | ((unsigned)a.w << 24);
    }
    __syncthreads();

    int lane = tid & 63, w = tid >> 6;   // 16 waves
    int lg = w & 3, sq = w >> 2;
    bool act = lane < 50;
    int dq = lane;

    // ---- Ax over m-quarter {7,6,6,6}, one-mg-ahead x prefetch ----
    float4 acc[4];
    #pragma unroll
    for (int i = 0; i < 4; ++i) acc[i] = make_float4(0.f, 0.f, 0.f, 0.f);
    if (act) {
        int mg0 = (sq == 0) ? 0 : 1 + 6 * sq;       // 0,7,13,19
        int mg1 = mg0 + ((sq == 0) ? 7 : 6);
        float4 xc[4], xn[4];
        #pragma unroll
        for (int mm = 0; mm < 4; ++mm)
            xc[mm] = x4[(size_t)(b * LL + 4 * mg0 + mm) * 50 + dq];
        for (int mg = mg0; mg < mg1; ++mg) {
            int mgn = (mg + 1 < mg1) ? mg + 1 : mg;   // dummy reload on last iter
            #pragma unroll
            for (int mm = 0; mm < 4; ++mm)
                xn[mm] = x4[(size_t)(b * LL + 4 * mgn + mm) * 50 + dq];
            unsigned ap[4];
            #pragma unroll
            for (int i = 0; i < 4; ++i) {
                int li = lg + 4 * i;
                ap[i] = (li < lcnt) ? adjp[li * 25 + mg] : 0u;
            }
            #pragma unroll
            for (int mm = 0; mm < 4; ++mm) {
                #pragma unroll
                for (int i = 0; i < 4; ++i) {
                    unsigned r = (ap[i] >> (8 * mm)) & 0xffu;
                    uint2 dv = deps_b[r * 50 + dq];
                    acc[i].x = fmaf(lo16(dv.x), xc[mm].x, acc[i].x);
                    acc[i].y = fmaf(hi16(dv.x), xc[mm].y, acc[i].y);
                    acc[i].z = fmaf(lo16(dv.y), xc[mm].z, acc[i].z);
                    acc[i].w = fmaf(hi16(dv.y), xc[mm].w, acc[i].w);
                }
            }
            #pragma unroll
            for (int mm = 0; mm < 4; ++mm) xc[mm] = xn[mm];
        }
        #pragma unroll
        for (int i = 0; i < 4; ++i) {
            int li = lg + 4 * i;
            if (li < lcnt) Sh[sq * 650 + li * 50 + dq] = acc[i];
        }
    }
    __syncthreads();

    // ---- reduce 4 slots + fp32 residual (writes Sfin over dead deps region) ----
    for (int t2 = tid; t2 < 650; t2 += 1024) {
        int li = t2 / 50;
        if (li < lcnt) {
            float4 s0 = Sh[t2], s1 = Sh[650 + t2], s2 = Sh[1300 + t2], s3 = Sh[1950 + t2];
            float4 xr = x4[(size_t)(b * LL + l0 + li) * 50 + (t2 % 50)];
            float4 s;
            s.x = s0.x + s1.x + s2.x + s3.x + xr.x;
            s.y = s0.y + s1.y + s2.y + s3.y + xr.y;
            s.z = s0.z + s1.z + s2.z + s3.z + xr.z;
            s.w = s0.w + s1.w + s2.w + s3.w + xr.w;
            Sfin[t2] = s;
        }
    }
    __syncthreads();

    // ---- GEMV over k-quarter {13,13,12,12}, pipelined, reuses Sh for partials ----
    const float4* wt4 = (const float4*)wt;
    int oq = act ? lane : 49;
    int kq0 = (sq < 2) ? 13 * sq : 26 + 12 * (sq - 2);  // 0,13,26,38
    int kcnt = (sq < 2) ? 13 : 12;
    int npair = kcnt >> 1;                              // 6
    int kqlast = kq0 + kcnt - 1;
    float4 ba[4];
    #pragma unroll
    for (int i = 0; i < 4; ++i) ba[i] = make_float4(0.f, 0.f, 0.f, 0.f);

    float4 wc[8], wn[8];
    #pragma unroll
    for (int q = 0; q < 2; ++q)
        #pragma unroll
        for (int j = 0; j < 4; ++j)
            wc[q * 4 + j] = wt4[(size_t)(4 * (kq0 + q) + j) * 50 + oq];

    int lic[4];
    #pragma unroll
    for (int i = 0; i < 4; ++i) {
        int li = lg + 4 * i;
        lic[i] = li < lcnt ? li : lcnt - 1;
    }

    for (int pr = 0; pr < npair; ++pr) {
        int nb = kq0 + 2 * pr + 2;
        int nbA = nb <= kqlast ? nb : kq0;
        int nbB = nb + 1 <= kqlast ? nb + 1 : kq0;
        #pragma unroll
        for (int j = 0; j < 4; ++j) wn[j]     = wt4[(size_t)(4 * nbA + j) * 50 + oq];
        #pragma unroll
        for (int j = 0; j < 4; ++j) wn[4 + j] = wt4[(size_t)(4 * nbB + j) * 50 + oq];
        #pragma unroll
        for (int q = 0; q < 2; ++q) {
            int kq = kq0 + 2 * pr + q;
            #pragma unroll
            for (int i = 0; i < 4; ++i) {
                float4 s = Sfin[lic[i] * 50 + kq];   // wave-uniform broadcast
                fma4(ba[i], wc[q * 4 + 0], s.x); fma4(ba[i], wc[q * 4 + 1], s.y);
                fma4(ba[i], wc[q * 4 + 2], s.z); fma4(ba[i], wc[q * 4 + 3], s.w);
            }
        }
        #pragma unroll
        for (int j = 0; j < 8; ++j) wc[j] = wn[j];
    }
    if (kcnt & 1) {   // tail quad kqlast (sits in wc[0..3])
        #pragma unroll
        for (int i = 0; i < 4; ++i) {
            float4 s = Sfin[lic[i] * 50 + kqlast];
            fma4(ba[i], wc[0], s.x); fma4(ba[i], wc[1], s.y);
            fma4(ba[i], wc[2], s.z); fma4(ba[i], wc[3], s.w);
        }
    }

    if (act) {
        #pragma unroll
        for (int i = 0; i < 4; ++i) {
            int li = lg + 4 * i;
            if (li < lcnt) Sh[sq * 650 + li * 50 + oq] = ba[i];
        }
    }
    __syncthreads();

    for (int t2 = tid; t2 < 650; t2 += 1024) {
        int li = t2 / 50, oq2 = t2 % 50;
        if (li < lcnt) {
            float4 v0 = Sh[t2], v1 = Sh[650 + t2], v2 = Sh[1300 + t2], v3 = Sh[1950 + t2];
            float4 bb = ((const float4*)bias)[oq2];
            int p = b * LL + l0 + li;
            float sc = invd[p];
            float4 v;
            v.x = fmaxf((v0.x + v1.x + v2.x + v3.x + 2.f * bb.x) * sc, 0.f);
            v.y = fmaxf((v0.y + v1.y + v2.y + v3.y + 2.f * bb.y) * sc, 0.f);
            v.z = fmaxf((v0.z + v1.z + v2.z + v3.z + 2.f * bb.z) * sc, 0.f);
            v.w = fmaxf((v0.w + v1.w + v2.w + v3.w + 2.f * bb.w) * sc, 0.f);
            ((float4*)out)[(size_t)p * 50 + oq2] = v;
        }
    }
}

extern "C" void kernel_launch(void* const* d_in, const int* in_sizes, int n_in,
                              void* d_out, int out_size, void* d_ws, size_t ws_size,
                              hipStream_t stream) {
    const int*   adj   = (const int*)d_in[0];
    const int*   words = (const int*)d_in[1];
    const int*   pos   = (const int*)d_in[2];
    const int*   ner   = (const int*)d_in[3];
    const float* emb   = (const float*)d_in[4];
    const float* pose  = (const float*)d_in[5];
    const float* nere  = (const float*)d_in[6];
    const float* dep   = (const float*)d_in[7];
    const float* Wp    = (const float*)d_in[8];
    const float* bp    = (const float*)d_in[9];
    const float* W0    = (const float*)d_in[10];
    const float* b0    = (const float*)d_in[11];
    const float* W1    = (const float*)d_in[12];
    const float* b1    = (const float*)d_in[13];
    float* out = (float*)d_out;
    float* ws  = (float*)d_ws;

    float* xA   = ws;                // 640,000
    float* xB   = ws + 640000;       // 640,000
    float* WpT  = ws + 1280000;      //  72,000
    float* W0T  = ws + 1352000;      //  40,000
    float* W1T  = ws + 1392000;      //  40,000
    float* invd = ws + 1432000;      //   3,200

    prep_transpose_kernel<<<25 + 149, 256, 0, stream>>>(adj, Wp, W0, W1, WpT, W0T, W1T,
                                                        invd, out + (size_t)NP * DD);
    embed_gemv_kernel<<<NP / 8, 512, 0, stream>>>(words, pos, ner, emb, pose, nere,
                                                  WpT, bp, xA);
    layer_kernel<<<dim3(NT, BB), 1024, 0, stream>>>(xA, adj, dep, W0T, b0, invd, xB);
    layer_kernel<<<dim3(NT, BB), 1024, 0, stream>>>(xB, adj, dep, W1T, b1, invd, out);
}